// Round 3
// baseline (441.100 us; speedup 1.0000x reference)
//
#include <hip/hip_runtime.h>
#include <hip/hip_bf16.h>
#include <math.h>

typedef __bf16 bf16;
typedef __bf16 bf16x8 __attribute__((ext_vector_type(8)));
typedef float floatx4 __attribute__((ext_vector_type(4)));

#define HIDDEN 1024
#define NHEADS 16
#define HDIM 64
#define TSEQ 2048
#define NBATCH 2
#define MTOT (NBATCH * TSEQ) /* 4096 */

// Load 8 consecutive elements as bf16x8, converting from f32 if needed.
template <bool F32>
__device__ inline bf16x8 load8(const void* base, size_t elem)
{
  if constexpr (F32) {
    const float* p = (const float*)base + elem;
    const floatx4 u = *(const floatx4*)p;
    const floatx4 v = *(const floatx4*)(p + 4);
    bf16x8 r;
#pragma unroll
    for (int j = 0; j < 4; j++) r[j] = (bf16)u[j];
#pragma unroll
    for (int j = 0; j < 4; j++) r[4 + j] = (bf16)v[j];
    return r;
  } else {
    return *(const bf16x8*)((const bf16*)base + elem);
  }
}

// ======================================================================
// GEMM: C[M,N] = A[M,K] @ W[N,K]^T + bias[N]   (f32-or-bf16 in, f32 acc)
// 128x128 tile, BK=32, 4 waves each owning a 64x64 subtile (4x4 MFMA 16x16x32).
// MODE 0: epilogue scatters columns into Q/K/V (b,h,t,d) bf16 buffers.
// MODE 1: plain row-major f32 store to C.
// C/D layout (verified m89/m91): col = lane&15, row = (lane>>4)*4 + reg.
// A frag: A[m=lane&15][k=quad*8+j]; B frag: B[k=quad*8+j][n=lane&15].
// W is stored [n][k] so B-fragments read 8 contiguous k.
// ======================================================================
template <int MODE, bool AF32, bool WF32>
__global__ __launch_bounds__(256) void gemm_bt(
    const void* __restrict__ A, const void* __restrict__ W,
    const float* __restrict__ bias, float* __restrict__ C,
    bf16* __restrict__ Qb, bf16* __restrict__ Kb, bf16* __restrict__ Vb,
    int M, int N, int K)
{
  __shared__ bf16 As[128 * 32];  // [m][k] row-major
  __shared__ bf16 Bs[128 * 32];  // [n][k] row-major

  const int tid  = threadIdx.x;
  const int lane = tid & 63;
  const int wv   = tid >> 6;
  const int quad = lane >> 4;
  const int l16  = lane & 15;
  const int m0 = blockIdx.y * 128;
  const int n0 = blockIdx.x * 128;
  const int wm = (wv >> 1) * 64;
  const int wn = (wv & 1) * 64;

  // staging: 512 chunks of 8 elements per matrix; 2 per thread
  const int c0  = tid * 2;
  const int c1  = c0 + 1;
  const int ar0 = c0 >> 2, ac0 = (c0 & 3) * 8;
  const int ar1 = c1 >> 2, ac1 = (c1 & 3) * 8;

  floatx4 acc[4][4];
#pragma unroll
  for (int i = 0; i < 4; i++)
#pragma unroll
    for (int j = 0; j < 4; j++) acc[i][j] = (floatx4){0.f, 0.f, 0.f, 0.f};

  for (int k0 = 0; k0 < K; k0 += 32) {
    bf16x8 av0 = load8<AF32>(A, (size_t)(m0 + ar0) * K + k0 + ac0);
    bf16x8 av1 = load8<AF32>(A, (size_t)(m0 + ar1) * K + k0 + ac1);
    bf16x8 bv0 = load8<WF32>(W, (size_t)(n0 + ar0) * K + k0 + ac0);
    bf16x8 bv1 = load8<WF32>(W, (size_t)(n0 + ar1) * K + k0 + ac1);
    __syncthreads();  // prev iter's LDS reads done before overwrite
    *(bf16x8*)(As + c0 * 8) = av0;
    *(bf16x8*)(As + c1 * 8) = av1;
    *(bf16x8*)(Bs + c0 * 8) = bv0;
    *(bf16x8*)(Bs + c1 * 8) = bv1;
    __syncthreads();

    bf16x8 af[4], bfr[4];
#pragma unroll
    for (int i = 0; i < 4; i++)
      af[i] = *(const bf16x8*)(As + (wm + i * 16 + l16) * 32 + quad * 8);
#pragma unroll
    for (int j = 0; j < 4; j++)
      bfr[j] = *(const bf16x8*)(Bs + (wn + j * 16 + l16) * 32 + quad * 8);
#pragma unroll
    for (int i = 0; i < 4; i++)
#pragma unroll
      for (int j = 0; j < 4; j++)
        acc[i][j] = __builtin_amdgcn_mfma_f32_16x16x32_bf16(af[i], bfr[j], acc[i][j], 0, 0, 0);
  }

  // epilogue
#pragma unroll
  for (int i = 0; i < 4; i++) {
    const int gmBase = m0 + wm + i * 16 + quad * 4;
#pragma unroll
    for (int j = 0; j < 4; j++) {
      const int gn = n0 + wn + j * 16 + l16;
      const float bs = bias[gn];
#pragma unroll
      for (int r = 0; r < 4; r++) {
        const int gm = gmBase + r;
        const float v = acc[i][j][r] + bs;
        if (MODE == 1) {
          C[(size_t)gm * N + gn] = v;
        } else {
          // n -> (which, head, d); m -> (b, t); write (b,h,t,d)
          const int which = gn >> 10;
          const int rem = gn & 1023;
          const int h = rem >> 6, d = rem & 63;
          const int b = gm >> 11, t = gm & 2047;
          bf16* dst = (which == 0) ? Qb : (which == 1) ? Kb : Vb;
          dst[((size_t)(b * NHEADS + h) * TSEQ + t) * HDIM + d] = (bf16)v;
        }
      }
    }
  }
}

// ======================================================================
// RoPE in-place on Q and K, (b,h,t,d) layout. ROPE_DIM==HEAD_DIM==64:
// out[i]    = x[i]*cos - x[i+32]*sin
// out[i+32] = x[i]*sin + x[i+32]*cos,  angle = t * 10000^(-i/32), i in [0,32)
// ======================================================================
__global__ __launch_bounds__(256) void rope_kernel(bf16* __restrict__ Q,
                                                   bf16* __restrict__ K)
{
  const int idx = blockIdx.x * 256 + threadIdx.x;  // bh*65536 + t*32 + i
  if (idx >= 32 * TSEQ * 32) return;
  const int i  = idx & 31;
  const int t  = (idx >> 5) & (TSEQ - 1);
  const int bh = idx >> 16;
  const float inv = powf(10000.0f, -(float)i * (1.0f / 32.0f));
  const float ang = (float)t * inv;
  float s, c;
  sincosf(ang, &s, &c);  // accurate range-reduction needed: t up to 2047 rad
  const size_t base = ((size_t)bh * TSEQ + t) * HDIM;
  {
    const float x1 = (float)Q[base + i], x2 = (float)Q[base + i + 32];
    Q[base + i]      = (bf16)(x1 * c - x2 * s);
    Q[base + i + 32] = (bf16)(x1 * s + x2 * c);
  }
  {
    const float x1 = (float)K[base + i], x2 = (float)K[base + i + 32];
    K[base + i]      = (bf16)(x1 * c - x2 * s);
    K[base + i + 32] = (bf16)(x1 * s + x2 * c);
  }
}

// ======================================================================
// V (b,h,t,d) -> Vt (b,h,d,t): makes PV B-fragments 16B-contiguous loads.
// ======================================================================
__global__ __launch_bounds__(256) void transpose_v(const bf16* __restrict__ V,
                                                   bf16* __restrict__ Vt)
{
  __shared__ bf16 tile[64][80];  // pad 64->80 to break bank conflicts
  const int bh = blockIdx.y;
  const int t0 = blockIdx.x * 64;
  const bf16* src = V + ((size_t)bh * TSEQ + t0) * HDIM;
  for (int c = threadIdx.x; c < 512; c += 256) {
    const int r = c >> 3, c8 = (c & 7) * 8;
    *(bf16x8*)&tile[r][c8] = *(const bf16x8*)(src + (size_t)r * HDIM + c8);
  }
  __syncthreads();
  bf16* dst = Vt + (size_t)bh * HDIM * TSEQ + t0;
  for (int c = threadIdx.x; c < 512; c += 256) {
    const int d = c >> 3, t8 = (c & 7) * 8;
    bf16x8 vv;
#pragma unroll
    for (int j = 0; j < 8; j++) vv[j] = tile[t8 + j][d];
    *(bf16x8*)(dst + (size_t)d * TSEQ + t8) = vv;
  }
}

// ======================================================================
// Flash attention. Grid (T/64, B*H), block 256 = 4 waves.
// Each wave: 16 q-rows, online softmax, K processed in chunks of 32 keys.
// S = Q·K^T via 4 MFMA; P -> LDS (real barriers) -> A-frag; PV via 4 MFMA.
// Mask: allow = (k <= q) || is_global(q)  [global mask indexes the QUERY].
// kmax is BLOCK-uniform (barrier legality).
// O written as (b, t, h*64+d) bf16 so the out-proj GEMM reads it row-major.
// ======================================================================
__global__ __launch_bounds__(256) void attn_kernel(
    const bf16* __restrict__ Q, const bf16* __restrict__ K,
    const bf16* __restrict__ Vt, bf16* __restrict__ O,
    const int* __restrict__ ids, const int* __restrict__ gidx)
{
  __shared__ bf16 Plds[4][16 * 32];  // per-wave P tile
  __shared__ int flags[4];

  const int tid  = threadIdx.x;
  const int lane = tid & 63;
  const int wv   = tid >> 6;
  const int quad = lane >> 4;
  const int l16  = lane & 15;
  const int bh = blockIdx.y;
  const int b  = bh >> 4;
  const int h  = bh & 15;
  const int q0 = blockIdx.x * 64 + wv * 16;

  const bf16* Qp = Q + (size_t)bh * TSEQ * HDIM;
  const bf16* Kp = K + (size_t)bh * TSEQ * HDIM;
  const bf16* Vp = Vt + (size_t)bh * HDIM * TSEQ;

  // Q fragments for this wave's 16 rows (persistent)
  const bf16x8 qf0 = *(const bf16x8*)(Qp + (size_t)(q0 + l16) * HDIM + quad * 8);
  const bf16x8 qf1 = *(const bf16x8*)(Qp + (size_t)(q0 + l16) * HDIM + 32 + quad * 8);

  // global-token flags for the 4 rows this lane's quad owns
  const int g0v = gidx[0], g1v = gidx[1], g2v = gidx[2];
  int g[4];
  int anyl = 0;
#pragma unroll
  for (int r = 0; r < 4; r++) {
    const int q = q0 + quad * 4 + r;
    const int id = ids[b * TSEQ + q];
    g[r] = (id == g0v) | (id == g1v) | (id == g2v);
    anyl |= g[r];
  }
  flags[wv] = __any(anyl);
  __syncthreads();
  const int anyg = flags[0] | flags[1] | flags[2] | flags[3];
  // block-uniform trip count (legalizes barriers in the loop)
  const int kmax = anyg ? TSEQ : (blockIdx.x * 64 + 64);

  float m_run[4] = {-1e30f, -1e30f, -1e30f, -1e30f};
  float l_run[4] = {0.f, 0.f, 0.f, 0.f};
  floatx4 o[4];
#pragma unroll
  for (int nt = 0; nt < 4; nt++) o[nt] = (floatx4){0.f, 0.f, 0.f, 0.f};

  for (int k0 = 0; k0 < kmax; k0 += 32) {
    // ---- S = Q·K^T (two 16-key column tiles) ----
    const bf16* kp = Kp + (size_t)(k0 + l16) * HDIM;
    const bf16x8 kf00 = *(const bf16x8*)(kp + quad * 8);
    const bf16x8 kf01 = *(const bf16x8*)(kp + 32 + quad * 8);
    const bf16x8 kf10 = *(const bf16x8*)(kp + 16 * HDIM + quad * 8);
    const bf16x8 kf11 = *(const bf16x8*)(kp + 16 * HDIM + 32 + quad * 8);
    floatx4 s0 = (floatx4){0.f, 0.f, 0.f, 0.f};
    floatx4 s1 = (floatx4){0.f, 0.f, 0.f, 0.f};
    s0 = __builtin_amdgcn_mfma_f32_16x16x32_bf16(qf0, kf00, s0, 0, 0, 0);
    s0 = __builtin_amdgcn_mfma_f32_16x16x32_bf16(qf1, kf01, s0, 0, 0, 0);
    s1 = __builtin_amdgcn_mfma_f32_16x16x32_bf16(qf0, kf10, s1, 0, 0, 0);
    s1 = __builtin_amdgcn_mfma_f32_16x16x32_bf16(qf1, kf11, s1, 0, 0, 0);

    // V fragments (issue early, consumed after softmax)
    bf16x8 vf[4];
#pragma unroll
    for (int nt = 0; nt < 4; nt++)
      vf[nt] = *(const bf16x8*)(Vp + (size_t)(nt * 16 + l16) * TSEQ + k0 + quad * 8);

    // ---- online softmax per row (row spread over 16 lanes of this quad) ----
#pragma unroll
    for (int r = 0; r < 4; r++) {
      const int q  = q0 + quad * 4 + r;
      const int ka = k0 + l16;
      const int kb = ka + 16;
      float v0 = (g[r] || ka <= q) ? s0[r] * 0.125f : -1e30f;
      float v1 = (g[r] || kb <= q) ? s1[r] * 0.125f : -1e30f;
      float mx = fmaxf(v0, v1);
      mx = fmaxf(mx, __shfl_xor(mx, 1));
      mx = fmaxf(mx, __shfl_xor(mx, 2));
      mx = fmaxf(mx, __shfl_xor(mx, 4));
      mx = fmaxf(mx, __shfl_xor(mx, 8));
      const float mnew = fmaxf(m_run[r], mx);
      const float al = __expf(m_run[r] - mnew);
      const float p0 = __expf(v0 - mnew);
      const float p1 = __expf(v1 - mnew);
      float sm = p0 + p1;
      sm += __shfl_xor(sm, 1);
      sm += __shfl_xor(sm, 2);
      sm += __shfl_xor(sm, 4);
      sm += __shfl_xor(sm, 8);
      l_run[r] = l_run[r] * al + sm;
      m_run[r] = mnew;
#pragma unroll
      for (int nt = 0; nt < 4; nt++) o[nt][r] *= al;
      const int row = quad * 4 + r;
      Plds[wv][row * 32 + l16]      = (bf16)p0;
      Plds[wv][row * 32 + 16 + l16] = (bf16)p1;
    }
    __syncthreads();  // P writes visible

    // P as A-fragment: A[m=l16][k=quad*8+j] -> one ds_read_b128
    const bf16x8 pf = *(const bf16x8*)(&Plds[wv][l16 * 32 + quad * 8]);
#pragma unroll
    for (int nt = 0; nt < 4; nt++)
      o[nt] = __builtin_amdgcn_mfma_f32_16x16x32_bf16(pf, vf[nt], o[nt], 0, 0, 0);
    __syncthreads();  // P reads done before next iteration's writes
  }

  // ---- normalize + store O (b, t, h*64+d) ----
#pragma unroll
  for (int r = 0; r < 4; r++) {
    const float inv = 1.0f / l_run[r];
    const int q = q0 + quad * 4 + r;
    const size_t rowoff = ((size_t)b * TSEQ + q) * HIDDEN + h * HDIM;
#pragma unroll
    for (int nt = 0; nt < 4; nt++)
      O[rowoff + nt * 16 + l16] = (bf16)(o[nt][r] * inv);
  }
}

// ======================================================================
extern "C" void kernel_launch(void* const* d_in, const int* in_sizes, int n_in,
                              void* d_out, int out_size, void* d_ws, size_t ws_size,
                              hipStream_t stream)
{
  // dtypes per the reference file: floats are float32, ints are int32,
  // output is float32. Internal pipeline converts to bf16 for MFMA.
  const void* x      = d_in[0];            // f32 [B,T,H]
  const int*  ids    = (const int*)d_in[1];
  const void* qkv_w  = d_in[2];            // f32 [3H,H]
  const float* qkv_b = (const float*)d_in[3];
  const void* out_w  = d_in[4];            // f32 [H,H]
  const float* out_b = (const float*)d_in[5];
  const int*  gidx   = (const int*)d_in[6];
  float* out = (float*)d_out;

  // workspace layout: 4 x 8 MiB = 32 MiB. O aliases V (V dead once Vt built).
  char* ws = (char*)d_ws;
  bf16* Q  = (bf16*)(ws);
  bf16* K  = (bf16*)(ws + (size_t)(8u << 20));
  bf16* V  = (bf16*)(ws + (size_t)(16u << 20));
  bf16* Vt = (bf16*)(ws + (size_t)(24u << 20));
  bf16* O  = V;  // alias

  // 1) QKV projection (f32 inputs -> bf16 MFMA), scatter to Q/K/V (b,h,t,d)
  gemm_bt<0, true, true><<<dim3(3072 / 128, MTOT / 128), 256, 0, stream>>>(
      x, qkv_w, qkv_b, nullptr, Q, K, V, MTOT, 3 * HIDDEN, HIDDEN);
  // 2) RoPE in-place on Q, K
  rope_kernel<<<(32 * TSEQ * 32) / 256, 256, 0, stream>>>(Q, K);
  // 3) V -> Vt
  transpose_v<<<dim3(TSEQ / 64, 32), 256, 0, stream>>>(V, Vt);
  // 4) flash attention -> O (b,t,hidden); O overwrites V
  attn_kernel<<<dim3(TSEQ / 64, 32), 256, 0, stream>>>(Q, K, Vt, O, ids, gidx);
  // 5) output projection -> d_out (f32)
  gemm_bt<1, false, true><<<dim3(HIDDEN / 128, MTOT / 128), 256, 0, stream>>>(
      O, out_w, out_b, out, nullptr, nullptr, nullptr, MTOT, HIDDEN, HIDDEN);
}

// Round 4
// 437.650 us; speedup vs baseline: 1.0079x; 1.0079x over previous
//
#include <hip/hip_runtime.h>
#include <hip/hip_bf16.h>
#include <math.h>

typedef __bf16 bf16;
typedef __bf16 bf16x8 __attribute__((ext_vector_type(8)));
typedef __bf16 bf16x4 __attribute__((ext_vector_type(4)));
typedef float floatx4 __attribute__((ext_vector_type(4)));

#define HIDDEN 1024
#define NHEADS 16
#define HDIM 64
#define TSEQ 2048
#define NBATCH 2
#define MTOT (NBATCH * TSEQ) /* 4096 */

// Load 8 consecutive elements as bf16x8, converting from f32 if needed.
template <bool F32>
__device__ inline bf16x8 load8(const void* base, size_t elem)
{
  if constexpr (F32) {
    const float* p = (const float*)base + elem;
    const floatx4 u = *(const floatx4*)p;
    const floatx4 v = *(const floatx4*)(p + 4);
    bf16x8 r;
#pragma unroll
    for (int j = 0; j < 4; j++) r[j] = (bf16)u[j];
#pragma unroll
    for (int j = 0; j < 4; j++) r[4 + j] = (bf16)v[j];
    return r;
  } else {
    return *(const bf16x8*)((const bf16*)base + elem);
  }
}

// ======================================================================
// GEMM: C[M,N] = A[M,K] @ W[N,K]^T + bias[N]   (f32-or-bf16 in, f32 acc)
// 128x128 tile, BK=32, 4 waves each owning a 64x64 subtile (4x4 MFMA 16x16x32).
// MODE 0: epilogue scatters columns into Q/K/V (b,h,t,d) bf16 buffers.
// MODE 1: plain row-major f32 store to C.
// ======================================================================
template <int MODE, bool AF32, bool WF32>
__global__ __launch_bounds__(256) void gemm_bt(
    const void* __restrict__ A, const void* __restrict__ W,
    const float* __restrict__ bias, float* __restrict__ C,
    bf16* __restrict__ Qb, bf16* __restrict__ Kb, bf16* __restrict__ Vb,
    int M, int N, int K)
{
  __shared__ bf16 As[128 * 32];  // [m][k] row-major
  __shared__ bf16 Bs[128 * 32];  // [n][k] row-major

  const int tid  = threadIdx.x;
  const int lane = tid & 63;
  const int wv   = tid >> 6;
  const int quad = lane >> 4;
  const int l16  = lane & 15;
  const int m0 = blockIdx.y * 128;
  const int n0 = blockIdx.x * 128;
  const int wm = (wv >> 1) * 64;
  const int wn = (wv & 1) * 64;

  // staging: 512 chunks of 8 elements per matrix; 2 per thread
  const int c0  = tid * 2;
  const int c1  = c0 + 1;
  const int ar0 = c0 >> 2, ac0 = (c0 & 3) * 8;
  const int ar1 = c1 >> 2, ac1 = (c1 & 3) * 8;

  floatx4 acc[4][4];
#pragma unroll
  for (int i = 0; i < 4; i++)
#pragma unroll
    for (int j = 0; j < 4; j++) acc[i][j] = (floatx4){0.f, 0.f, 0.f, 0.f};

  for (int k0 = 0; k0 < K; k0 += 32) {
    bf16x8 av0 = load8<AF32>(A, (size_t)(m0 + ar0) * K + k0 + ac0);
    bf16x8 av1 = load8<AF32>(A, (size_t)(m0 + ar1) * K + k0 + ac1);
    bf16x8 bv0 = load8<WF32>(W, (size_t)(n0 + ar0) * K + k0 + ac0);
    bf16x8 bv1 = load8<WF32>(W, (size_t)(n0 + ar1) * K + k0 + ac1);
    __syncthreads();  // prev iter's LDS reads done before overwrite
    *(bf16x8*)(As + c0 * 8) = av0;
    *(bf16x8*)(As + c1 * 8) = av1;
    *(bf16x8*)(Bs + c0 * 8) = bv0;
    *(bf16x8*)(Bs + c1 * 8) = bv1;
    __syncthreads();

    bf16x8 af[4], bfr[4];
#pragma unroll
    for (int i = 0; i < 4; i++)
      af[i] = *(const bf16x8*)(As + (wm + i * 16 + l16) * 32 + quad * 8);
#pragma unroll
    for (int j = 0; j < 4; j++)
      bfr[j] = *(const bf16x8*)(Bs + (wn + j * 16 + l16) * 32 + quad * 8);
#pragma unroll
    for (int i = 0; i < 4; i++)
#pragma unroll
      for (int j = 0; j < 4; j++)
        acc[i][j] = __builtin_amdgcn_mfma_f32_16x16x32_bf16(af[i], bfr[j], acc[i][j], 0, 0, 0);
  }

  // epilogue
#pragma unroll
  for (int i = 0; i < 4; i++) {
    const int gmBase = m0 + wm + i * 16 + quad * 4;
#pragma unroll
    for (int j = 0; j < 4; j++) {
      const int gn = n0 + wn + j * 16 + l16;
      const float bs = bias[gn];
#pragma unroll
      for (int r = 0; r < 4; r++) {
        const int gm = gmBase + r;
        const float v = acc[i][j][r] + bs;
        if (MODE == 1) {
          C[(size_t)gm * N + gn] = v;
        } else {
          // n -> (which, head, d); m -> (b, t); write (b,h,t,d)
          const int which = gn >> 10;
          const int rem = gn & 1023;
          const int h = rem >> 6, d = rem & 63;
          const int b = gm >> 11, t = gm & 2047;
          bf16* dst = (which == 0) ? Qb : (which == 1) ? Kb : Vb;
          dst[((size_t)(b * NHEADS + h) * TSEQ + t) * HDIM + d] = (bf16)v;
        }
      }
    }
  }
}

// ======================================================================
// RoPE in-place on Q and K, (b,h,t,d) layout. ROPE_DIM==HEAD_DIM==64.
// ======================================================================
__global__ __launch_bounds__(256) void rope_kernel(bf16* __restrict__ Q,
                                                   bf16* __restrict__ K)
{
  const int idx = blockIdx.x * 256 + threadIdx.x;  // bh*65536 + t*32 + i
  if (idx >= 32 * TSEQ * 32) return;
  const int i  = idx & 31;
  const int t  = (idx >> 5) & (TSEQ - 1);
  const int bh = idx >> 16;
  const float inv = powf(10000.0f, -(float)i * (1.0f / 32.0f));
  const float ang = (float)t * inv;
  float s, c;
  sincosf(ang, &s, &c);
  const size_t base = ((size_t)bh * TSEQ + t) * HDIM;
  {
    const float x1 = (float)Q[base + i], x2 = (float)Q[base + i + 32];
    Q[base + i]      = (bf16)(x1 * c - x2 * s);
    Q[base + i + 32] = (bf16)(x1 * s + x2 * c);
  }
  {
    const float x1 = (float)K[base + i], x2 = (float)K[base + i + 32];
    K[base + i]      = (bf16)(x1 * c - x2 * s);
    K[base + i + 32] = (bf16)(x1 * s + x2 * c);
  }
}

// ======================================================================
// V (b,h,t,d) -> Vt (b,h,d,t)
// ======================================================================
__global__ __launch_bounds__(256) void transpose_v(const bf16* __restrict__ V,
                                                   bf16* __restrict__ Vt)
{
  __shared__ bf16 tile[64][80];
  const int bh = blockIdx.y;
  const int t0 = blockIdx.x * 64;
  const bf16* src = V + ((size_t)bh * TSEQ + t0) * HDIM;
  for (int c = threadIdx.x; c < 512; c += 256) {
    const int r = c >> 3, c8 = (c & 7) * 8;
    *(bf16x8*)&tile[r][c8] = *(const bf16x8*)(src + (size_t)r * HDIM + c8);
  }
  __syncthreads();
  bf16* dst = Vt + (size_t)bh * HDIM * TSEQ + t0;
  for (int c = threadIdx.x; c < 512; c += 256) {
    const int d = c >> 3, t8 = (c & 7) * 8;
    bf16x8 vv;
#pragma unroll
    for (int j = 0; j < 8; j++) vv[j] = tile[t8 + j][d];
    *(bf16x8*)(dst + (size_t)d * TSEQ + t8) = vv;
  }
}

// ======================================================================
// Flash attention v2. Grid (T/64, B*H), block 256 = 4 independent waves.
// Per wave: 16 q-rows, 64-key chunks, NO running max (scores ~N(0,1),
// fp32 exp safe to 88 sigma), per-lane deferred l-sum (no in-loop shfl),
// no block barriers (wave-private P round-trip, fence = lgkmcnt wait).
// P LDS row stride 68: write bank = 8*quad+2r+8kt+l16/2 -> conflict-free;
// reads via 8B-aligned ds_read_b64 pairs.
// kmax per-wave: q0+16 causal, TSEQ if any of the wave's rows is global.
// q-tiles reversed so triangular-largest blocks launch first.
// ======================================================================
#define PSTRIDE 68
__global__ __launch_bounds__(256) void attn_kernel(
    const bf16* __restrict__ Q, const bf16* __restrict__ K,
    const bf16* __restrict__ Vt, bf16* __restrict__ O,
    const int* __restrict__ ids, const int* __restrict__ gidx)
{
  __shared__ bf16 Plds[4][16 * PSTRIDE];

  const int tid  = threadIdx.x;
  const int lane = tid & 63;
  const int wv   = tid >> 6;
  const int quad = lane >> 4;
  const int l16  = lane & 15;
  const int bh = blockIdx.y;
  const int b  = bh >> 4;
  const int h  = bh & 15;
  const int qt = gridDim.x - 1 - blockIdx.x;  // biggest work first
  const int q0 = qt * 64 + wv * 16;

  const bf16* Qp = Q + (size_t)bh * TSEQ * HDIM;
  const bf16* Kp = K + (size_t)bh * TSEQ * HDIM;
  const bf16* Vp = Vt + (size_t)bh * HDIM * TSEQ;

  // Q fragments for this wave's 16 rows (persistent)
  const bf16x8 qf0 = *(const bf16x8*)(Qp + (size_t)(q0 + l16) * HDIM + quad * 8);
  const bf16x8 qf1 = *(const bf16x8*)(Qp + (size_t)(q0 + l16) * HDIM + 32 + quad * 8);

  // global-token flags for the 4 rows this lane's quad owns
  const int g0v = gidx[0], g1v = gidx[1], g2v = gidx[2];
  int g[4];
  int anyl = 0;
#pragma unroll
  for (int r = 0; r < 4; r++) {
    const int q = q0 + quad * 4 + r;
    const int id = ids[b * TSEQ + q];
    g[r] = (id == g0v) | (id == g1v) | (id == g2v);
    anyl |= g[r];
  }
  const bool anyg = __any(anyl);
  const int kmax = anyg ? TSEQ : (q0 + 16);  // wave-uniform

  float lsum[4] = {0.f, 0.f, 0.f, 0.f};
  floatx4 o[4];
#pragma unroll
  for (int nt = 0; nt < 4; nt++) o[nt] = (floatx4){0.f, 0.f, 0.f, 0.f};

  for (int k0 = 0; k0 < kmax; k0 += 64) {
    // ---- S = Q.K^T : 4 tiles of 16 keys ----
    floatx4 s[4];
#pragma unroll
    for (int kt = 0; kt < 4; kt++) {
      const bf16* kp = Kp + (size_t)(k0 + kt * 16 + l16) * HDIM + quad * 8;
      const bf16x8 kfa = *(const bf16x8*)kp;
      const bf16x8 kfb = *(const bf16x8*)(kp + 32);
      floatx4 z = (floatx4){0.f, 0.f, 0.f, 0.f};
      z = __builtin_amdgcn_mfma_f32_16x16x32_bf16(qf0, kfa, z, 0, 0, 0);
      s[kt] = __builtin_amdgcn_mfma_f32_16x16x32_bf16(qf1, kfb, z, 0, 0, 0);
    }

    // V fragments (issue early, consumed after softmax)
    bf16x8 vf[4][2];
#pragma unroll
    for (int nt = 0; nt < 4; nt++)
#pragma unroll
      for (int ks = 0; ks < 2; ks++)
        vf[nt][ks] = *(const bf16x8*)(Vp + (size_t)(nt * 16 + l16) * TSEQ + k0 + ks * 32 + quad * 8);

    // ---- softmax numerator: p = exp(s/8) (no max shift), masked -> 0 ----
#pragma unroll
    for (int kt = 0; kt < 4; kt++) {
      const int key = k0 + kt * 16 + l16;
#pragma unroll
      for (int r = 0; r < 4; r++) {
        const int q = q0 + quad * 4 + r;
        const bool ok = g[r] || (key <= q);
        const float p = ok ? __expf(s[kt][r] * 0.125f) : 0.f;
        lsum[r] += p;
        Plds[wv][(quad * 4 + r) * PSTRIDE + kt * 16 + l16] = (bf16)p;
      }
    }
    __threadfence_block();  // drain P writes (wave-private; lgkmcnt wait)

    // P as A-fragment: A[m=l16][k=quad*8+j+32*ks]; 8B-aligned b64 pairs
    bf16x8 pf[2];
#pragma unroll
    for (int ks = 0; ks < 2; ks++) {
      const bf16* pp = &Plds[wv][l16 * PSTRIDE + ks * 32 + quad * 8];
      const bf16x4 lo = *(const bf16x4*)pp;
      const bf16x4 hi = *(const bf16x4*)(pp + 4);
      bf16x8 f;
#pragma unroll
      for (int j = 0; j < 4; j++) { f[j] = lo[j]; f[4 + j] = hi[j]; }
      pf[ks] = f;
    }
#pragma unroll
    for (int nt = 0; nt < 4; nt++) {
      o[nt] = __builtin_amdgcn_mfma_f32_16x16x32_bf16(pf[0], vf[nt][0], o[nt], 0, 0, 0);
      o[nt] = __builtin_amdgcn_mfma_f32_16x16x32_bf16(pf[1], vf[nt][1], o[nt], 0, 0, 0);
    }
    __threadfence_block();  // P reads complete before next iter's writes
  }

  // ---- final l reduction over the quad's 16 lanes, then store ----
#pragma unroll
  for (int r = 0; r < 4; r++) {
    float s = lsum[r];
    s += __shfl_xor(s, 1);
    s += __shfl_xor(s, 2);
    s += __shfl_xor(s, 4);
    s += __shfl_xor(s, 8);
    lsum[r] = s;
  }
#pragma unroll
  for (int r = 0; r < 4; r++) {
    const float inv = 1.0f / lsum[r];
    const int q = q0 + quad * 4 + r;
    const size_t rowoff = ((size_t)b * TSEQ + q) * HIDDEN + h * HDIM;
#pragma unroll
    for (int nt = 0; nt < 4; nt++)
      O[rowoff + nt * 16 + l16] = (bf16)(o[nt][r] * inv);
  }
}

// ======================================================================
extern "C" void kernel_launch(void* const* d_in, const int* in_sizes, int n_in,
                              void* d_out, int out_size, void* d_ws, size_t ws_size,
                              hipStream_t stream)
{
  const void* x      = d_in[0];            // f32 [B,T,H]
  const int*  ids    = (const int*)d_in[1];
  const void* qkv_w  = d_in[2];            // f32 [3H,H]
  const float* qkv_b = (const float*)d_in[3];
  const void* out_w  = d_in[4];            // f32 [H,H]
  const float* out_b = (const float*)d_in[5];
  const int*  gidx   = (const int*)d_in[6];
  float* out = (float*)d_out;

  // workspace layout: 4 x 8 MiB = 32 MiB. O aliases V (V dead once Vt built).
  char* ws = (char*)d_ws;
  bf16* Q  = (bf16*)(ws);
  bf16* K  = (bf16*)(ws + (size_t)(8u << 20));
  bf16* V  = (bf16*)(ws + (size_t)(16u << 20));
  bf16* Vt = (bf16*)(ws + (size_t)(24u << 20));
  bf16* O  = V;  // alias

  // 1) QKV projection (f32 inputs -> bf16 MFMA), scatter to Q/K/V (b,h,t,d)
  gemm_bt<0, true, true><<<dim3(3072 / 128, MTOT / 128), 256, 0, stream>>>(
      x, qkv_w, qkv_b, nullptr, Q, K, V, MTOT, 3 * HIDDEN, HIDDEN);
  // 2) RoPE in-place on Q, K
  rope_kernel<<<(32 * TSEQ * 32) / 256, 256, 0, stream>>>(Q, K);
  // 3) V -> Vt
  transpose_v<<<dim3(TSEQ / 64, 32), 256, 0, stream>>>(V, Vt);
  // 4) flash attention -> O (b,t,hidden); O overwrites V
  attn_kernel<<<dim3(TSEQ / 64, 32), 256, 0, stream>>>(Q, K, Vt, O, ids, gidx);
  // 5) output projection -> d_out (f32)
  gemm_bt<1, false, true><<<dim3(HIDDEN / 128, MTOT / 128), 256, 0, stream>>>(
      O, out_w, out_b, out, nullptr, nullptr, nullptr, MTOT, HIDDEN, HIDDEN);
}

// Round 5
// 437.358 us; speedup vs baseline: 1.0086x; 1.0007x over previous
//
#include <hip/hip_runtime.h>
#include <hip/hip_bf16.h>
#include <math.h>

typedef __bf16 bf16;
typedef __bf16 bf16x8 __attribute__((ext_vector_type(8)));
typedef __bf16 bf16x4 __attribute__((ext_vector_type(4)));
typedef float floatx4 __attribute__((ext_vector_type(4)));

#define HIDDEN 1024
#define NHEADS 16
#define HDIM 64
#define TSEQ 2048
#define NBATCH 2
#define MTOT (NBATCH * TSEQ) /* 4096 */

// Load 8 consecutive elements as bf16x8, converting from f32 if needed.
template <bool F32>
__device__ inline bf16x8 load8(const void* base, size_t elem)
{
  if constexpr (F32) {
    const float* p = (const float*)base + elem;
    const floatx4 u = *(const floatx4*)p;
    const floatx4 v = *(const floatx4*)(p + 4);
    bf16x8 r;
#pragma unroll
    for (int j = 0; j < 4; j++) r[j] = (bf16)u[j];
#pragma unroll
    for (int j = 0; j < 4; j++) r[4 + j] = (bf16)v[j];
    return r;
  } else {
    return *(const bf16x8*)((const bf16*)base + elem);
  }
}

// ======================================================================
// GEMM: C[M,N] = A[M,K] @ W[N,K]^T + bias[N]   (f32-or-bf16 in, f32 acc)
// 128x128 tile, BK=32, 4 waves each owning a 64x64 subtile (4x4 MFMA 16x16x32).
// MODE 0: epilogue scatters columns into Q/K/V (b,h,t,d) bf16 buffers.
// MODE 1: plain row-major f32 store to C.
// ======================================================================
template <int MODE, bool AF32, bool WF32>
__global__ __launch_bounds__(256) void gemm_bt(
    const void* __restrict__ A, const void* __restrict__ W,
    const float* __restrict__ bias, float* __restrict__ C,
    bf16* __restrict__ Qb, bf16* __restrict__ Kb, bf16* __restrict__ Vb,
    int M, int N, int K)
{
  __shared__ bf16 As[128 * 32];  // [m][k] row-major
  __shared__ bf16 Bs[128 * 32];  // [n][k] row-major

  const int tid  = threadIdx.x;
  const int lane = tid & 63;
  const int wv   = tid >> 6;
  const int quad = lane >> 4;
  const int l16  = lane & 15;
  const int m0 = blockIdx.y * 128;
  const int n0 = blockIdx.x * 128;
  const int wm = (wv >> 1) * 64;
  const int wn = (wv & 1) * 64;

  // staging: 512 chunks of 8 elements per matrix; 2 per thread
  const int c0  = tid * 2;
  const int c1  = c0 + 1;
  const int ar0 = c0 >> 2, ac0 = (c0 & 3) * 8;
  const int ar1 = c1 >> 2, ac1 = (c1 & 3) * 8;

  floatx4 acc[4][4];
#pragma unroll
  for (int i = 0; i < 4; i++)
#pragma unroll
    for (int j = 0; j < 4; j++) acc[i][j] = (floatx4){0.f, 0.f, 0.f, 0.f};

  for (int k0 = 0; k0 < K; k0 += 32) {
    bf16x8 av0 = load8<AF32>(A, (size_t)(m0 + ar0) * K + k0 + ac0);
    bf16x8 av1 = load8<AF32>(A, (size_t)(m0 + ar1) * K + k0 + ac1);
    bf16x8 bv0 = load8<WF32>(W, (size_t)(n0 + ar0) * K + k0 + ac0);
    bf16x8 bv1 = load8<WF32>(W, (size_t)(n0 + ar1) * K + k0 + ac1);
    __syncthreads();  // prev iter's LDS reads done before overwrite
    *(bf16x8*)(As + c0 * 8) = av0;
    *(bf16x8*)(As + c1 * 8) = av1;
    *(bf16x8*)(Bs + c0 * 8) = bv0;
    *(bf16x8*)(Bs + c1 * 8) = bv1;
    __syncthreads();

    bf16x8 af[4], bfr[4];
#pragma unroll
    for (int i = 0; i < 4; i++)
      af[i] = *(const bf16x8*)(As + (wm + i * 16 + l16) * 32 + quad * 8);
#pragma unroll
    for (int j = 0; j < 4; j++)
      bfr[j] = *(const bf16x8*)(Bs + (wn + j * 16 + l16) * 32 + quad * 8);
#pragma unroll
    for (int i = 0; i < 4; i++)
#pragma unroll
      for (int j = 0; j < 4; j++)
        acc[i][j] = __builtin_amdgcn_mfma_f32_16x16x32_bf16(af[i], bfr[j], acc[i][j], 0, 0, 0);
  }

  // epilogue
#pragma unroll
  for (int i = 0; i < 4; i++) {
    const int gmBase = m0 + wm + i * 16 + quad * 4;
#pragma unroll
    for (int j = 0; j < 4; j++) {
      const int gn = n0 + wn + j * 16 + l16;
      const float bs = bias[gn];
#pragma unroll
      for (int r = 0; r < 4; r++) {
        const int gm = gmBase + r;
        const float v = acc[i][j][r] + bs;
        if (MODE == 1) {
          C[(size_t)gm * N + gn] = v;
        } else {
          // n -> (which, head, d); m -> (b, t); write (b,h,t,d)
          const int which = gn >> 10;
          const int rem = gn & 1023;
          const int h = rem >> 6, d = rem & 63;
          const int b = gm >> 11, t = gm & 2047;
          bf16* dst = (which == 0) ? Qb : (which == 1) ? Kb : Vb;
          dst[((size_t)(b * NHEADS + h) * TSEQ + t) * HDIM + d] = (bf16)v;
        }
      }
    }
  }
}

// ======================================================================
// RoPE in-place on Q and K, (b,h,t,d) layout. ROPE_DIM==HEAD_DIM==64.
// ======================================================================
__global__ __launch_bounds__(256) void rope_kernel(bf16* __restrict__ Q,
                                                   bf16* __restrict__ K)
{
  const int idx = blockIdx.x * 256 + threadIdx.x;  // bh*65536 + t*32 + i
  if (idx >= 32 * TSEQ * 32) return;
  const int i  = idx & 31;
  const int t  = (idx >> 5) & (TSEQ - 1);
  const int bh = idx >> 16;
  const float inv = powf(10000.0f, -(float)i * (1.0f / 32.0f));
  const float ang = (float)t * inv;
  float s, c;
  sincosf(ang, &s, &c);
  const size_t base = ((size_t)bh * TSEQ + t) * HDIM;
  {
    const float x1 = (float)Q[base + i], x2 = (float)Q[base + i + 32];
    Q[base + i]      = (bf16)(x1 * c - x2 * s);
    Q[base + i + 32] = (bf16)(x1 * s + x2 * c);
  }
  {
    const float x1 = (float)K[base + i], x2 = (float)K[base + i + 32];
    K[base + i]      = (bf16)(x1 * c - x2 * s);
    K[base + i + 32] = (bf16)(x1 * s + x2 * c);
  }
}

// ======================================================================
// V (b,h,t,d) -> Vt (b,h,d,t)
// ======================================================================
__global__ __launch_bounds__(256) void transpose_v(const bf16* __restrict__ V,
                                                   bf16* __restrict__ Vt)
{
  __shared__ bf16 tile[64][80];
  const int bh = blockIdx.y;
  const int t0 = blockIdx.x * 64;
  const bf16* src = V + ((size_t)bh * TSEQ + t0) * HDIM;
  for (int c = threadIdx.x; c < 512; c += 256) {
    const int r = c >> 3, c8 = (c & 7) * 8;
    *(bf16x8*)&tile[r][c8] = *(const bf16x8*)(src + (size_t)r * HDIM + c8);
  }
  __syncthreads();
  bf16* dst = Vt + (size_t)bh * HDIM * TSEQ + t0;
  for (int c = threadIdx.x; c < 512; c += 256) {
    const int d = c >> 3, t8 = (c & 7) * 8;
    bf16x8 vv;
#pragma unroll
    for (int j = 0; j < 8; j++) vv[j] = tile[t8 + j][d];
    *(bf16x8*)(dst + (size_t)d * TSEQ + t8) = vv;
  }
}

// ======================================================================
// Flash attention v3 — ZERO LDS, zero fences, pure register dataflow.
// Grid (T/64, B*H), block 256 = 4 independent waves; wave = 16 q-rows.
//
// Trick: compute S^T = K.Q^T (operands swapped) over PERMUTED key tiles:
//   tile0 rows: G0(m) = (m>>2)*8 + (m&3); tile1: G0(m)+4.
// S^T C/D layout => lane(l16,quad) reg r holds S[query=q0+l16][key=kb+quad*8+r]
// (tile0) and key=kb+quad*8+4+r (tile1) — which IS the A-fragment layout
// A[m=l16][k=quad*8+j] of mfma_f32_16x16x32_bf16 for the PV product over a
// natural 32-key group. So exp() is applied in-register and fed straight
// to PV MFMA; V B-frags are contiguous 16B loads from Vt (d,t).
// No running max: scores ~N(0,1), fp32 exp safe far beyond observed range.
// l-sum: one scalar per lane (query=l16), reduced across quads at the end.
// kmax per-wave: q0+16 causal, TSEQ if any of the wave's 16 queries is
// a global token. q-tiles reversed so biggest blocks launch first.
// ======================================================================
__global__ __launch_bounds__(256) void attn_kernel(
    const bf16* __restrict__ Q, const bf16* __restrict__ K,
    const bf16* __restrict__ Vt, bf16* __restrict__ O,
    const int* __restrict__ ids, const int* __restrict__ gidx)
{
  const int tid  = threadIdx.x;
  const int lane = tid & 63;
  const int wv   = tid >> 6;
  const int quad = lane >> 4;
  const int l16  = lane & 15;
  const int bh = blockIdx.y;
  const int b  = bh >> 4;
  const int h  = bh & 15;
  const int qt = gridDim.x - 1 - blockIdx.x;  // biggest work first
  const int q0 = qt * 64 + wv * 16;

  const bf16* Qp = Q + (size_t)bh * TSEQ * HDIM;
  const bf16* Kp = K + (size_t)bh * TSEQ * HDIM;
  const bf16* Vp = Vt + (size_t)bh * HDIM * TSEQ;

  // Q fragments (B-operand of S^T): B[k=quad*8+j][n=l16] = Q[q0+l16][d]
  const bf16x8 qf0 = *(const bf16x8*)(Qp + (size_t)(q0 + l16) * HDIM + quad * 8);
  const bf16x8 qf1 = *(const bf16x8*)(Qp + (size_t)(q0 + l16) * HDIM + 32 + quad * 8);

  // this lane's query and its global-token flag
  const int g0v = gidx[0], g1v = gidx[1], g2v = gidx[2];
  const int myq = q0 + l16;
  const int myid = ids[b * TSEQ + myq];
  const int gl = (myid == g0v) | (myid == g1v) | (myid == g2v);
  const bool anyg = __any(gl);
  const int kmax = anyg ? TSEQ : (q0 + 16);  // wave-uniform

  // permuted K-row index for S^T tiles
  const int perm = ((l16 >> 2) << 3) + (l16 & 3);  // tile0 row; tile1 = +4

  float lsum = 0.f;
  floatx4 o[4];
#pragma unroll
  for (int nt = 0; nt < 4; nt++) o[nt] = (floatx4){0.f, 0.f, 0.f, 0.f};

  for (int k0 = 0; k0 < kmax; k0 += 64) {
#pragma unroll
    for (int kt = 0; kt < 2; kt++) {
      const int kb = k0 + kt * 32;  // 32-key PV group
      // ---- S^T tiles (A = permuted K rows, B = Q) ----
      const bf16* kp0 = Kp + (size_t)(kb + perm) * HDIM + quad * 8;
      const bf16* kp1 = Kp + (size_t)(kb + perm + 4) * HDIM + quad * 8;
      const bf16x8 ka0 = *(const bf16x8*)kp0;         // d 0..31
      const bf16x8 ka1 = *(const bf16x8*)(kp0 + 32);  // d 32..63
      const bf16x8 kb0 = *(const bf16x8*)kp1;
      const bf16x8 kb1 = *(const bf16x8*)(kp1 + 32);
      floatx4 s0 = (floatx4){0.f, 0.f, 0.f, 0.f};
      floatx4 s1 = (floatx4){0.f, 0.f, 0.f, 0.f};
      s0 = __builtin_amdgcn_mfma_f32_16x16x32_bf16(ka0, qf0, s0, 0, 0, 0);
      s0 = __builtin_amdgcn_mfma_f32_16x16x32_bf16(ka1, qf1, s0, 0, 0, 0);
      s1 = __builtin_amdgcn_mfma_f32_16x16x32_bf16(kb0, qf0, s1, 0, 0, 0);
      s1 = __builtin_amdgcn_mfma_f32_16x16x32_bf16(kb1, qf1, s1, 0, 0, 0);

      // ---- exp + mask in-register; pack into PV A-fragment ----
      bf16x8 pf;
#pragma unroll
      for (int r = 0; r < 4; r++) {
        const int key0 = kb + quad * 8 + r;      // from tile0
        const int key1 = key0 + 4;               // from tile1
        const float p0 = (gl || key0 <= myq) ? __expf(s0[r] * 0.125f) : 0.f;
        const float p1 = (gl || key1 <= myq) ? __expf(s1[r] * 0.125f) : 0.f;
        lsum += p0 + p1;
        pf[r]     = (bf16)p0;
        pf[4 + r] = (bf16)p1;
      }

      // ---- PV over the natural 32-key group ----
#pragma unroll
      for (int nt = 0; nt < 4; nt++) {
        const bf16x8 vf = *(const bf16x8*)(Vp + (size_t)(nt * 16 + l16) * TSEQ + kb + quad * 8);
        o[nt] = __builtin_amdgcn_mfma_f32_16x16x32_bf16(pf, vf, o[nt], 0, 0, 0);
      }
    }
  }

  // ---- reduce l across the 4 quads (lanes sharing l16), redistribute ----
  lsum += __shfl_xor(lsum, 16);
  lsum += __shfl_xor(lsum, 32);  // lane now has full sum for query q0+l16

#pragma unroll
  for (int r = 0; r < 4; r++) {
    const float inv = 1.0f / __shfl(lsum, quad * 4 + r);  // sum for query quad*4+r
    const int q = q0 + quad * 4 + r;
    const size_t rowoff = ((size_t)b * TSEQ + q) * HIDDEN + h * HDIM;
#pragma unroll
    for (int nt = 0; nt < 4; nt++)
      O[rowoff + nt * 16 + l16] = (bf16)(o[nt][r] * inv);
  }
}

// ======================================================================
extern "C" void kernel_launch(void* const* d_in, const int* in_sizes, int n_in,
                              void* d_out, int out_size, void* d_ws, size_t ws_size,
                              hipStream_t stream)
{
  const void* x      = d_in[0];            // f32 [B,T,H]
  const int*  ids    = (const int*)d_in[1];
  const void* qkv_w  = d_in[2];            // f32 [3H,H]
  const float* qkv_b = (const float*)d_in[3];
  const void* out_w  = d_in[4];            // f32 [H,H]
  const float* out_b = (const float*)d_in[5];
  const int*  gidx   = (const int*)d_in[6];
  float* out = (float*)d_out;

  // workspace layout: 4 x 8 MiB = 32 MiB. O aliases V (V dead once Vt built).
  char* ws = (char*)d_ws;
  bf16* Q  = (bf16*)(ws);
  bf16* K  = (bf16*)(ws + (size_t)(8u << 20));
  bf16* V  = (bf16*)(ws + (size_t)(16u << 20));
  bf16* Vt = (bf16*)(ws + (size_t)(24u << 20));
  bf16* O  = V;  // alias

  // 1) QKV projection (f32 inputs -> bf16 MFMA), scatter to Q/K/V (b,h,t,d)
  gemm_bt<0, true, true><<<dim3(3072 / 128, MTOT / 128), 256, 0, stream>>>(
      x, qkv_w, qkv_b, nullptr, Q, K, V, MTOT, 3 * HIDDEN, HIDDEN);
  // 2) RoPE in-place on Q, K
  rope_kernel<<<(32 * TSEQ * 32) / 256, 256, 0, stream>>>(Q, K);
  // 3) V -> Vt
  transpose_v<<<dim3(TSEQ / 64, 32), 256, 0, stream>>>(V, Vt);
  // 4) flash attention -> O (b,t,hidden); O overwrites V
  attn_kernel<<<dim3(TSEQ / 64, 32), 256, 0, stream>>>(Q, K, Vt, O, ids, gidx);
  // 5) output projection -> d_out (f32)
  gemm_bt<1, false, true><<<dim3(HIDDEN / 128, MTOT / 128), 256, 0, stream>>>(
      O, out_w, out_b, out, nullptr, nullptr, nullptr, MTOT, HIDDEN, HIDDEN);
}

// Round 6
// 311.169 us; speedup vs baseline: 1.4176x; 1.4055x over previous
//
#include <hip/hip_runtime.h>
#include <hip/hip_bf16.h>
#include <math.h>

typedef __bf16 bf16;
typedef __bf16 bf16x8 __attribute__((ext_vector_type(8)));
typedef float floatx4 __attribute__((ext_vector_type(4)));

#define HIDDEN 1024
#define NHEADS 16
#define HDIM 64
#define TSEQ 2048
#define NBATCH 2
#define MTOT (NBATCH * TSEQ) /* 4096 */

// Load 8 consecutive elements as bf16x8, converting from f32 if needed.
template <bool F32>
__device__ inline bf16x8 load8(const void* base, size_t elem)
{
  if constexpr (F32) {
    const float* p = (const float*)base + elem;
    const floatx4 u = *(const floatx4*)p;
    const floatx4 v = *(const floatx4*)(p + 4);
    bf16x8 r;
#pragma unroll
    for (int j = 0; j < 4; j++) r[j] = (bf16)u[j];
#pragma unroll
    for (int j = 0; j < 4; j++) r[4 + j] = (bf16)v[j];
    return r;
  } else {
    return *(const bf16x8*)((const bf16*)base + elem);
  }
}

// ======================================================================
// GEMM: C[M,N] = A[M,K] @ W[N,K]^T + bias[N]   (f32-or-bf16 in, f32 acc)
// 128x128 tile, BK=32, 4 waves each owning a 64x64 subtile (4x4 MFMA 16x16x32).
// MODE 0: epilogue scatters columns into Q/K/V (b,h,t,d) bf16 buffers.
// MODE 1: plain row-major f32 store to C.
// ======================================================================
template <int MODE, bool AF32, bool WF32>
__global__ __launch_bounds__(256) void gemm_bt(
    const void* __restrict__ A, const void* __restrict__ W,
    const float* __restrict__ bias, float* __restrict__ C,
    bf16* __restrict__ Qb, bf16* __restrict__ Kb, bf16* __restrict__ Vb,
    int M, int N, int K)
{
  __shared__ bf16 As[128 * 32];  // [m][k] row-major
  __shared__ bf16 Bs[128 * 32];  // [n][k] row-major

  const int tid  = threadIdx.x;
  const int lane = tid & 63;
  const int wv   = tid >> 6;
  const int quad = lane >> 4;
  const int l16  = lane & 15;
  const int m0 = blockIdx.y * 128;
  const int n0 = blockIdx.x * 128;
  const int wm = (wv >> 1) * 64;
  const int wn = (wv & 1) * 64;

  // staging: 512 chunks of 8 elements per matrix; 2 per thread
  const int c0  = tid * 2;
  const int c1  = c0 + 1;
  const int ar0 = c0 >> 2, ac0 = (c0 & 3) * 8;
  const int ar1 = c1 >> 2, ac1 = (c1 & 3) * 8;

  floatx4 acc[4][4];
#pragma unroll
  for (int i = 0; i < 4; i++)
#pragma unroll
    for (int j = 0; j < 4; j++) acc[i][j] = (floatx4){0.f, 0.f, 0.f, 0.f};

  for (int k0 = 0; k0 < K; k0 += 32) {
    bf16x8 av0 = load8<AF32>(A, (size_t)(m0 + ar0) * K + k0 + ac0);
    bf16x8 av1 = load8<AF32>(A, (size_t)(m0 + ar1) * K + k0 + ac1);
    bf16x8 bv0 = load8<WF32>(W, (size_t)(n0 + ar0) * K + k0 + ac0);
    bf16x8 bv1 = load8<WF32>(W, (size_t)(n0 + ar1) * K + k0 + ac1);
    __syncthreads();  // prev iter's LDS reads done before overwrite
    *(bf16x8*)(As + c0 * 8) = av0;
    *(bf16x8*)(As + c1 * 8) = av1;
    *(bf16x8*)(Bs + c0 * 8) = bv0;
    *(bf16x8*)(Bs + c1 * 8) = bv1;
    __syncthreads();

    bf16x8 af[4], bfr[4];
#pragma unroll
    for (int i = 0; i < 4; i++)
      af[i] = *(const bf16x8*)(As + (wm + i * 16 + l16) * 32 + quad * 8);
#pragma unroll
    for (int j = 0; j < 4; j++)
      bfr[j] = *(const bf16x8*)(Bs + (wn + j * 16 + l16) * 32 + quad * 8);
#pragma unroll
    for (int i = 0; i < 4; i++)
#pragma unroll
      for (int j = 0; j < 4; j++)
        acc[i][j] = __builtin_amdgcn_mfma_f32_16x16x32_bf16(af[i], bfr[j], acc[i][j], 0, 0, 0);
  }

  // epilogue
#pragma unroll
  for (int i = 0; i < 4; i++) {
    const int gmBase = m0 + wm + i * 16 + quad * 4;
#pragma unroll
    for (int j = 0; j < 4; j++) {
      const int gn = n0 + wn + j * 16 + l16;
      const float bs = bias[gn];
#pragma unroll
      for (int r = 0; r < 4; r++) {
        const int gm = gmBase + r;
        const float v = acc[i][j][r] + bs;
        if (MODE == 1) {
          C[(size_t)gm * N + gn] = v;
        } else {
          // n -> (which, head, d); m -> (b, t); write (b,h,t,d)
          const int which = gn >> 10;
          const int rem = gn & 1023;
          const int h = rem >> 6, d = rem & 63;
          const int b = gm >> 11, t = gm & 2047;
          bf16* dst = (which == 0) ? Qb : (which == 1) ? Kb : Vb;
          dst[((size_t)(b * NHEADS + h) * TSEQ + t) * HDIM + d] = (bf16)v;
        }
      }
    }
  }
}

// ======================================================================
// RoPE in-place on Q and K, (b,h,t,d) layout. ROPE_DIM==HEAD_DIM==64.
// ======================================================================
__global__ __launch_bounds__(256) void rope_kernel(bf16* __restrict__ Q,
                                                   bf16* __restrict__ K)
{
  const int idx = blockIdx.x * 256 + threadIdx.x;  // bh*65536 + t*32 + i
  if (idx >= 32 * TSEQ * 32) return;
  const int i  = idx & 31;
  const int t  = (idx >> 5) & (TSEQ - 1);
  const int bh = idx >> 16;
  const float inv = powf(10000.0f, -(float)i * (1.0f / 32.0f));
  const float ang = (float)t * inv;
  float s, c;
  sincosf(ang, &s, &c);
  const size_t base = ((size_t)bh * TSEQ + t) * HDIM;
  {
    const float x1 = (float)Q[base + i], x2 = (float)Q[base + i + 32];
    Q[base + i]      = (bf16)(x1 * c - x2 * s);
    Q[base + i + 32] = (bf16)(x1 * s + x2 * c);
  }
  {
    const float x1 = (float)K[base + i], x2 = (float)K[base + i + 32];
    K[base + i]      = (bf16)(x1 * c - x2 * s);
    K[base + i + 32] = (bf16)(x1 * s + x2 * c);
  }
}

// ======================================================================
// V (b,h,t,d) -> Vt (b,h,d,t)
// ======================================================================
__global__ __launch_bounds__(256) void transpose_v(const bf16* __restrict__ V,
                                                   bf16* __restrict__ Vt)
{
  __shared__ bf16 tile[64][80];
  const int bh = blockIdx.y;
  const int t0 = blockIdx.x * 64;
  const bf16* src = V + ((size_t)bh * TSEQ + t0) * HDIM;
  for (int c = threadIdx.x; c < 512; c += 256) {
    const int r = c >> 3, c8 = (c & 7) * 8;
    *(bf16x8*)&tile[r][c8] = *(const bf16x8*)(src + (size_t)r * HDIM + c8);
  }
  __syncthreads();
  bf16* dst = Vt + (size_t)bh * HDIM * TSEQ + t0;
  for (int c = threadIdx.x; c < 512; c += 256) {
    const int d = c >> 3, t8 = (c & 7) * 8;
    bf16x8 vv;
#pragma unroll
    for (int j = 0; j < 8; j++) vv[j] = tile[t8 + j][d];
    *(bf16x8*)(dst + (size_t)d * TSEQ + t8) = vv;
  }
}

// ======================================================================
// Flash attention v4 — cooperative LDS staging (m97 GEMM shape).
// Grid (T/64, B*H), block 256 = 4 waves; wave owns 16 q-rows.
// Per 64-key chunk the BLOCK stages K (8 KB, contiguous -> fully coalesced)
// and Vt (8 KB, 128B segments) into LDS, PRE-SWIZZLED into MFMA fragment
// order: every wave ds_read is lane*16B linear (conflict-free); staging
// writes are 2-way bank aliased (free). 4 waves share the staged bytes
// (4x traffic cut vs v3); staging loads are batch-issued (high MLP).
// S^T = K.Q^T permutation trick + in-register exp + PV (no P round-trip).
// kmax block-uniform; chunk count identical to per-wave causal count.
// ======================================================================
__global__ __launch_bounds__(256) void attn_kernel(
    const bf16* __restrict__ Q, const bf16* __restrict__ K,
    const bf16* __restrict__ Vt, bf16* __restrict__ O,
    const int* __restrict__ ids, const int* __restrict__ gidx)
{
  __shared__ bf16 Ks[4096];  // 8 KB: [g][tile][dhalf][lane] 16B units
  __shared__ bf16 Vs[4096];  // 8 KB: [g][nt][lane] 16B units
  __shared__ int flags[4];

  const int tid  = threadIdx.x;
  const int lane = tid & 63;
  const int wv   = tid >> 6;
  const int quad = lane >> 4;
  const int l16  = lane & 15;
  const int bh = blockIdx.y;
  const int b  = bh >> 4;
  const int h  = bh & 15;
  const int qt = gridDim.x - 1 - blockIdx.x;  // biggest work first
  const int q0b = qt * 64;
  const int q0 = q0b + wv * 16;

  const bf16* Qp = Q + (size_t)bh * TSEQ * HDIM;
  const bf16* Kp = K + (size_t)bh * TSEQ * HDIM;
  const bf16* Vp = Vt + (size_t)bh * HDIM * TSEQ;

  // Q fragments (B-operand of S^T): B[k=quad*8+j][n=l16] = Q[q0+l16][d]
  const bf16x8 qf0 = *(const bf16x8*)(Qp + (size_t)(q0 + l16) * HDIM + quad * 8);
  const bf16x8 qf1 = *(const bf16x8*)(Qp + (size_t)(q0 + l16) * HDIM + 32 + quad * 8);

  // this lane's query + global flag; block-uniform kmax
  const int g0v = gidx[0], g1v = gidx[1], g2v = gidx[2];
  const int myq = q0 + l16;
  const int myid = ids[b * TSEQ + myq];
  const int gl = (myid == g0v) | (myid == g1v) | (myid == g2v);
  flags[wv] = __any(gl);
  __syncthreads();
  const int anyg = flags[0] | flags[1] | flags[2] | flags[3];
  const int kmax = anyg ? TSEQ : (q0b + 64);

  // ---- staging decode (constant per thread) ----
  // K: thread t holds K[k0 + r][dc*8..+8], r = t>>3 (+32 for 2nd load), dc = t&7
  // fragment slot: tile=(r>>2)&1, m=((r>>3)<<2)|(r&3), dhalf=dc>>2, quadw=dc&3
  // dest elems: g*2048 + tile*1024 + dhalf*512 + (quadw*16+m)*8   (g = r>>5)
  const int rK  = tid >> 3;
  const int dcK = tid & 7;
  const int tileK = (rK >> 2) & 1;
  const int mK = ((rK >> 3) << 2) | (rK & 3);
  const int kdst = tileK * 1024 + (dcK >> 2) * 512 + (((dcK & 3) * 16 + mK) * 8);
  // V: thread t holds Vt[d][k0 + u*8], d = t>>3 (+32 for 2nd), u = t&7
  // dest: g*2048 + nt*512 + (quadw*16 + (d&15))*8,  g=u>>2, quadw=u&3, nt=d>>4
  const int dV = tid >> 3;
  const int uV = tid & 7;
  const int vdst = (uV >> 2) * 2048 + (dV >> 4) * 512 + (((uV & 3) * 16 + (dV & 15)) * 8);

  float lsum = 0.f;
  floatx4 o[4];
#pragma unroll
  for (int nt = 0; nt < 4; nt++) o[nt] = (floatx4){0.f, 0.f, 0.f, 0.f};

  for (int k0 = 0; k0 < kmax; k0 += 64) {
    // ---- batch-issue staging loads (high MLP, coalesced) ----
    const bf16* kc = Kp + (size_t)k0 * HDIM;  // 64 K rows = 8 KB contiguous
    const bf16x8 kA = *(const bf16x8*)(kc + tid * 8);
    const bf16x8 kB = *(const bf16x8*)(kc + 2048 + tid * 8);
    const bf16x8 vA = *(const bf16x8*)(Vp + (size_t)dV * TSEQ + k0 + uV * 8);
    const bf16x8 vB = *(const bf16x8*)(Vp + (size_t)(dV + 32) * TSEQ + k0 + uV * 8);
    __syncthreads();  // prev chunk's LDS reads complete
    *(bf16x8*)(Ks + kdst) = kA;              // rK<32 -> g=0
    *(bf16x8*)(Ks + kdst + 2048) = kB;       // rK+32 -> g=1, same slot
    *(bf16x8*)(Vs + vdst) = vA;              // dV<32 -> nt 0..1
    *(bf16x8*)(Vs + vdst + 1024) = vB;       // dV+32 -> nt 2..3 (+2*512)
    __syncthreads();

    // ---- compute: 2 groups of 32 keys ----
#pragma unroll
    for (int g = 0; g < 2; g++) {
      const int kb = k0 + g * 32;
      const bf16* kg = Ks + g * 2048 + lane * 8;
      const bf16x8 a00 = *(const bf16x8*)(kg);          // tile0, d 0..31
      const bf16x8 a01 = *(const bf16x8*)(kg + 512);    // tile0, d 32..63
      const bf16x8 a10 = *(const bf16x8*)(kg + 1024);   // tile1, d 0..31
      const bf16x8 a11 = *(const bf16x8*)(kg + 1536);   // tile1, d 32..63
      floatx4 s0 = (floatx4){0.f, 0.f, 0.f, 0.f};
      floatx4 s1 = (floatx4){0.f, 0.f, 0.f, 0.f};
      s0 = __builtin_amdgcn_mfma_f32_16x16x32_bf16(a00, qf0, s0, 0, 0, 0);
      s0 = __builtin_amdgcn_mfma_f32_16x16x32_bf16(a01, qf1, s0, 0, 0, 0);
      s1 = __builtin_amdgcn_mfma_f32_16x16x32_bf16(a10, qf0, s1, 0, 0, 0);
      s1 = __builtin_amdgcn_mfma_f32_16x16x32_bf16(a11, qf1, s1, 0, 0, 0);

      // exp + mask in-register; pack into PV A-fragment
      bf16x8 pf;
#pragma unroll
      for (int r = 0; r < 4; r++) {
        const int key0 = kb + quad * 8 + r;  // tile0
        const int key1 = key0 + 4;           // tile1
        const float p0 = (gl || key0 <= myq) ? __expf(s0[r] * 0.125f) : 0.f;
        const float p1 = (gl || key1 <= myq) ? __expf(s1[r] * 0.125f) : 0.f;
        lsum += p0 + p1;
        pf[r]     = (bf16)p0;
        pf[4 + r] = (bf16)p1;
      }

      // PV over the 32-key group; V frags linear from LDS
      const bf16* vg = Vs + g * 2048 + lane * 8;
#pragma unroll
      for (int nt = 0; nt < 4; nt++) {
        const bf16x8 vf = *(const bf16x8*)(vg + nt * 512);
        o[nt] = __builtin_amdgcn_mfma_f32_16x16x32_bf16(pf, vf, o[nt], 0, 0, 0);
      }
    }
  }

  // ---- reduce l across the 4 quads (lanes sharing l16), then store ----
  lsum += __shfl_xor(lsum, 16);
  lsum += __shfl_xor(lsum, 32);  // lane holds full sum for query q0+l16

#pragma unroll
  for (int r = 0; r < 4; r++) {
    const float inv = 1.0f / __shfl(lsum, quad * 4 + r);
    const int q = q0 + quad * 4 + r;
    const size_t rowoff = ((size_t)b * TSEQ + q) * HIDDEN + h * HDIM;
#pragma unroll
    for (int nt = 0; nt < 4; nt++)
      O[rowoff + nt * 16 + l16] = (bf16)(o[nt][r] * inv);
  }
}

// ======================================================================
extern "C" void kernel_launch(void* const* d_in, const int* in_sizes, int n_in,
                              void* d_out, int out_size, void* d_ws, size_t ws_size,
                              hipStream_t stream)
{
  const void* x      = d_in[0];            // f32 [B,T,H]
  const int*  ids    = (const int*)d_in[1];
  const void* qkv_w  = d_in[2];            // f32 [3H,H]
  const float* qkv_b = (const float*)d_in[3];
  const void* out_w  = d_in[4];            // f32 [H,H]
  const float* out_b = (const float*)d_in[5];
  const int*  gidx   = (const int*)d_in[6];
  float* out = (float*)d_out;

  // workspace layout: 4 x 8 MiB = 32 MiB. O aliases V (V dead once Vt built).
  char* ws = (char*)d_ws;
  bf16* Q  = (bf16*)(ws);
  bf16* K  = (bf16*)(ws + (size_t)(8u << 20));
  bf16* V  = (bf16*)(ws + (size_t)(16u << 20));
  bf16* Vt = (bf16*)(ws + (size_t)(24u << 20));
  bf16* O  = V;  // alias

  // 1) QKV projection (f32 inputs -> bf16 MFMA), scatter to Q/K/V (b,h,t,d)
  gemm_bt<0, true, true><<<dim3(3072 / 128, MTOT / 128), 256, 0, stream>>>(
      x, qkv_w, qkv_b, nullptr, Q, K, V, MTOT, 3 * HIDDEN, HIDDEN);
  // 2) RoPE in-place on Q, K
  rope_kernel<<<(32 * TSEQ * 32) / 256, 256, 0, stream>>>(Q, K);
  // 3) V -> Vt
  transpose_v<<<dim3(TSEQ / 64, 32), 256, 0, stream>>>(V, Vt);
  // 4) flash attention -> O (b,t,hidden); O overwrites V
  attn_kernel<<<dim3(TSEQ / 64, 32), 256, 0, stream>>>(Q, K, Vt, O, ids, gidx);
  // 5) output projection -> d_out (f32)
  gemm_bt<1, false, true><<<dim3(HIDDEN / 128, MTOT / 128), 256, 0, stream>>>(
      O, out_w, out_b, out, nullptr, nullptr, nullptr, MTOT, HIDDEN, HIDDEN);
}

// Round 7
// 214.896 us; speedup vs baseline: 2.0526x; 1.4480x over previous
//
#include <hip/hip_runtime.h>
#include <hip/hip_bf16.h>
#include <math.h>

typedef __bf16 bf16;
typedef __bf16 bf16x8 __attribute__((ext_vector_type(8)));
typedef float floatx4 __attribute__((ext_vector_type(4)));

#define HIDDEN 1024
#define NHEADS 16
#define HDIM 64
#define TSEQ 2048
#define NBATCH 2
#define MTOT (NBATCH * TSEQ) /* 4096 */

// ---- async 16B global->LDS (m97: the 874 TF enabler). lds must be wave-uniform. ----
__device__ inline void glds16(bf16* lds, const bf16* g)
{
  __builtin_amdgcn_global_load_lds(
      (const __attribute__((address_space(1))) unsigned int*)g,
      (__attribute__((address_space(3))) unsigned int*)lds, 16, 0, 0);
}

// ======================================================================
// f32 -> bf16 bulk convert (8 elems/thread, fully coalesced)
// ======================================================================
__global__ __launch_bounds__(256) void cvt_f32_bf16(
    const float* __restrict__ src, bf16* __restrict__ dst, int n)
{
  const int i = (blockIdx.x * 256 + threadIdx.x) * 8;
  if (i >= n) return;
  const floatx4 u = *(const floatx4*)(src + i);
  const floatx4 v = *(const floatx4*)(src + i + 4);
  bf16x8 r;
#pragma unroll
  for (int j = 0; j < 4; j++) { r[j] = (bf16)u[j]; r[4 + j] = (bf16)v[j]; }
  *(bf16x8*)(dst + i) = r;
}

// ======================================================================
// GEMM (pure bf16, m97 structure): C[M,N] = A[M,K] @ W[N,K]^T + bias[N]
// 128x128 tile, BK=32, 4 waves, 4x4 MFMA 16x16x32, global_load_lds width=16.
// MODE 0: scatter into Q/K/V (b,h,t,d). MODE 1: row-major f32 store.
// ======================================================================
template <int MODE>
__global__ __launch_bounds__(256) void gemm_bt(
    const bf16* __restrict__ A, const bf16* __restrict__ W,
    const float* __restrict__ bias, float* __restrict__ C,
    bf16* __restrict__ Qb, bf16* __restrict__ Kb, bf16* __restrict__ Vb,
    int M, int N, int K)
{
  __shared__ bf16 As[128 * 32];  // [m][k]
  __shared__ bf16 Bs[128 * 32];  // [n][k]

  const int tid  = threadIdx.x;
  const int lane = tid & 63;
  const int wv   = tid >> 6;
  const int quad = lane >> 4;
  const int l16  = lane & 15;
  const int m0 = blockIdx.y * 128;
  const int n0 = blockIdx.x * 128;
  const int wm = (wv >> 1) * 64;
  const int wn = (wv & 1) * 64;

  // glds geometry: wave wv covers rows wv*32..+31 (2 insts x 16 rows);
  // lane L -> row srow=L>>2, col (L&3)*8; LDS dest = base + L*16B (HW rule).
  const int srow = lane >> 2;
  const int scol = (lane & 3) * 8;

  floatx4 acc[4][4];
#pragma unroll
  for (int i = 0; i < 4; i++)
#pragma unroll
    for (int j = 0; j < 4; j++) acc[i][j] = (floatx4){0.f, 0.f, 0.f, 0.f};

  for (int k0 = 0; k0 < K; k0 += 32) {
    __syncthreads();  // prev iter's ds_reads done before overwrite
    const bf16* ga = A + (size_t)(m0 + wv * 32 + srow) * K + k0 + scol;
    glds16(As + (wv * 32) * 32, ga);
    glds16(As + (wv * 32 + 16) * 32, ga + (size_t)16 * K);
    const bf16* gb = W + (size_t)(n0 + wv * 32 + srow) * K + k0 + scol;
    glds16(Bs + (wv * 32) * 32, gb);
    glds16(Bs + (wv * 32 + 16) * 32, gb + (size_t)16 * K);
    __syncthreads();  // barrier drains vmcnt -> LDS populated

    bf16x8 af[4], bfr[4];
#pragma unroll
    for (int i = 0; i < 4; i++)
      af[i] = *(const bf16x8*)(As + (wm + i * 16 + l16) * 32 + quad * 8);
#pragma unroll
    for (int j = 0; j < 4; j++)
      bfr[j] = *(const bf16x8*)(Bs + (wn + j * 16 + l16) * 32 + quad * 8);
#pragma unroll
    for (int i = 0; i < 4; i++)
#pragma unroll
      for (int j = 0; j < 4; j++)
        acc[i][j] = __builtin_amdgcn_mfma_f32_16x16x32_bf16(af[i], bfr[j], acc[i][j], 0, 0, 0);
  }

  // epilogue
#pragma unroll
  for (int i = 0; i < 4; i++) {
    const int gmBase = m0 + wm + i * 16 + quad * 4;
#pragma unroll
    for (int j = 0; j < 4; j++) {
      const int gn = n0 + wn + j * 16 + l16;
      const float bs = bias[gn];
#pragma unroll
      for (int r = 0; r < 4; r++) {
        const int gm = gmBase + r;
        const float v = acc[i][j][r] + bs;
        if (MODE == 1) {
          C[(size_t)gm * N + gn] = v;
        } else {
          const int which = gn >> 10;
          const int rem = gn & 1023;
          const int h = rem >> 6, d = rem & 63;
          const int b = gm >> 11, t = gm & 2047;
          bf16* dst = (which == 0) ? Qb : (which == 1) ? Kb : Vb;
          dst[((size_t)(b * NHEADS + h) * TSEQ + t) * HDIM + d] = (bf16)v;
        }
      }
    }
  }
}

// ======================================================================
// RoPE in-place on Q and K, (b,h,t,d) layout.
// ======================================================================
__global__ __launch_bounds__(256) void rope_kernel(bf16* __restrict__ Q,
                                                   bf16* __restrict__ K)
{
  const int idx = blockIdx.x * 256 + threadIdx.x;
  if (idx >= 32 * TSEQ * 32) return;
  const int i  = idx & 31;
  const int t  = (idx >> 5) & (TSEQ - 1);
  const int bh = idx >> 16;
  const float inv = powf(10000.0f, -(float)i * (1.0f / 32.0f));
  const float ang = (float)t * inv;
  float s, c;
  sincosf(ang, &s, &c);
  const size_t base = ((size_t)bh * TSEQ + t) * HDIM;
  {
    const float x1 = (float)Q[base + i], x2 = (float)Q[base + i + 32];
    Q[base + i]      = (bf16)(x1 * c - x2 * s);
    Q[base + i + 32] = (bf16)(x1 * s + x2 * c);
  }
  {
    const float x1 = (float)K[base + i], x2 = (float)K[base + i + 32];
    K[base + i]      = (bf16)(x1 * c - x2 * s);
    K[base + i + 32] = (bf16)(x1 * s + x2 * c);
  }
}

// ======================================================================
// V (b,h,t,d) -> Vt (b,h,d,t)
// ======================================================================
__global__ __launch_bounds__(256) void transpose_v(const bf16* __restrict__ V,
                                                   bf16* __restrict__ Vt)
{
  __shared__ bf16 tile[64][80];
  const int bh = blockIdx.y;
  const int t0 = blockIdx.x * 64;
  const bf16* src = V + ((size_t)bh * TSEQ + t0) * HDIM;
  for (int c = threadIdx.x; c < 512; c += 256) {
    const int r = c >> 3, c8 = (c & 7) * 8;
    *(bf16x8*)&tile[r][c8] = *(const bf16x8*)(src + (size_t)r * HDIM + c8);
  }
  __syncthreads();
  bf16* dst = Vt + (size_t)bh * HDIM * TSEQ + t0;
  for (int c = threadIdx.x; c < 512; c += 256) {
    const int d = c >> 3, t8 = (c & 7) * 8;
    bf16x8 vv;
#pragma unroll
    for (int j = 0; j < 8; j++) vv[j] = tile[t8 + j][d];
    *(bf16x8*)(dst + (size_t)d * TSEQ + t8) = vv;
  }
}

// ---- XOR granule swizzle: spreads staging writes across all 8 bank-groups
// while keeping lane-linear reads conflict-free (granule = 16B unit). ----
__device__ inline int swz(int g) { return (g & ~7) | ((g ^ (g >> 3) ^ (g >> 6)) & 7); }

// ======================================================================
// Flash attention v5. Grid (16, B*H), block 256 = 4 waves.
// Balanced pairing: block processes q-tiles {blockIdx.x, 31-blockIdx.x}
// sequentially -> every block = 33 chunks (perfect load balance).
// Per 64-key chunk: register-prefetch of chunk k+1 issued before chunk k's
// compute (hides global latency); staged K/V in LDS in MFMA fragment order
// with XOR bank swizzle; S^T = K.Q^T permuted-tile trick; in-register exp;
// PV straight from registers. kmax block-uniform.
// ======================================================================
__global__ __launch_bounds__(256) void attn_kernel(
    const bf16* __restrict__ Q, const bf16* __restrict__ K,
    const bf16* __restrict__ Vt, bf16* __restrict__ O,
    const int* __restrict__ ids, const int* __restrict__ gidx)
{
  __shared__ bf16 Ks[4096];  // 8 KB, 512 granules, swizzled fragment order
  __shared__ bf16 Vs[4096];
  __shared__ int flags[4];

  const int tid  = threadIdx.x;
  const int lane = tid & 63;
  const int wv   = tid >> 6;
  const int quad = lane >> 4;
  const int l16  = lane & 15;
  const int bh = blockIdx.y;
  const int b  = bh >> 4;
  const int h  = bh & 15;

  const bf16* Qp = Q + (size_t)bh * TSEQ * HDIM;
  const bf16* Kp = K + (size_t)bh * TSEQ * HDIM;
  const bf16* Vp = Vt + (size_t)bh * HDIM * TSEQ;

  // staging decode (constant per thread)
  const int rK  = tid >> 3;
  const int dcK = tid & 7;
  const int gk = ((rK >> 2) & 1) * 128 + (dcK >> 2) * 64 +
                 ((dcK & 3) * 16 + (((rK >> 3) << 2) | (rK & 3)));
  const int kd0 = swz(gk) * 8, kd1 = swz(gk + 256) * 8;
  const int dV = tid >> 3;
  const int uV = tid & 7;
  const int gv = (uV >> 2) * 256 + (dV >> 4) * 64 + ((uV & 3) * 16 + (dV & 15));
  const int vd0 = swz(gv) * 8, vd1 = swz(gv + 128) * 8;

  const int g0v = gidx[0], g1v = gidx[1], g2v = gidx[2];

#pragma unroll
  for (int ph = 0; ph < 2; ph++) {
    const int qt = ph ? (31 - (int)blockIdx.x) : (int)blockIdx.x;
    const int q0 = qt * 64 + wv * 16;

    // Q fragments (B-operand of S^T)
    const bf16x8 qf0 = *(const bf16x8*)(Qp + (size_t)(q0 + l16) * HDIM + quad * 8);
    const bf16x8 qf1 = *(const bf16x8*)(Qp + (size_t)(q0 + l16) * HDIM + 32 + quad * 8);

    const int myq = q0 + l16;
    const int myid = ids[b * TSEQ + myq];
    const int gl = (myid == g0v) | (myid == g1v) | (myid == g2v);
    flags[wv] = __any(gl);
    __syncthreads();
    const int anyg = flags[0] | flags[1] | flags[2] | flags[3];
    const int kmax = anyg ? TSEQ : (qt * 64 + 64);  // block-uniform

    float lsum = 0.f;
    floatx4 o[4];
#pragma unroll
    for (int nt = 0; nt < 4; nt++) o[nt] = (floatx4){0.f, 0.f, 0.f, 0.f};

    // prologue loads for chunk 0
    bf16x8 kA = *(const bf16x8*)(Kp + tid * 8);
    bf16x8 kB = *(const bf16x8*)(Kp + 2048 + tid * 8);
    bf16x8 vA = *(const bf16x8*)(Vp + (size_t)dV * TSEQ + uV * 8);
    bf16x8 vB = *(const bf16x8*)(Vp + (size_t)(dV + 32) * TSEQ + uV * 8);

    for (int k0 = 0; k0 < kmax; k0 += 64) {
      __syncthreads();  // prev chunk's ds_reads complete
      *(bf16x8*)(Ks + kd0) = kA;
      *(bf16x8*)(Ks + kd1) = kB;
      *(bf16x8*)(Vs + vd0) = vA;
      *(bf16x8*)(Vs + vd1) = vB;
      __syncthreads();

      // prefetch next chunk (vmcnt-wait lands AFTER this chunk's compute)
      if (k0 + 64 < kmax) {
        const bf16* kc = Kp + (size_t)(k0 + 64) * HDIM;
        kA = *(const bf16x8*)(kc + tid * 8);
        kB = *(const bf16x8*)(kc + 2048 + tid * 8);
        vA = *(const bf16x8*)(Vp + (size_t)dV * TSEQ + k0 + 64 + uV * 8);
        vB = *(const bf16x8*)(Vp + (size_t)(dV + 32) * TSEQ + k0 + 64 + uV * 8);
      }

      // compute: 2 groups of 32 keys
#pragma unroll
      for (int g = 0; g < 2; g++) {
        const int kb = k0 + g * 32;
        const int rb = g * 256 + lane;
        const bf16x8 a00 = *(const bf16x8*)(Ks + swz(rb) * 8);
        const bf16x8 a01 = *(const bf16x8*)(Ks + swz(rb + 64) * 8);
        const bf16x8 a10 = *(const bf16x8*)(Ks + swz(rb + 128) * 8);
        const bf16x8 a11 = *(const bf16x8*)(Ks + swz(rb + 192) * 8);
        floatx4 s0 = (floatx4){0.f, 0.f, 0.f, 0.f};
        floatx4 s1 = (floatx4){0.f, 0.f, 0.f, 0.f};
        s0 = __builtin_amdgcn_mfma_f32_16x16x32_bf16(a00, qf0, s0, 0, 0, 0);
        s0 = __builtin_amdgcn_mfma_f32_16x16x32_bf16(a01, qf1, s0, 0, 0, 0);
        s1 = __builtin_amdgcn_mfma_f32_16x16x32_bf16(a10, qf0, s1, 0, 0, 0);
        s1 = __builtin_amdgcn_mfma_f32_16x16x32_bf16(a11, qf1, s1, 0, 0, 0);

        bf16x8 pf;
#pragma unroll
        for (int r = 0; r < 4; r++) {
          const int key0 = kb + quad * 8 + r;
          const int key1 = key0 + 4;
          const float p0 = (gl || key0 <= myq) ? __expf(s0[r] * 0.125f) : 0.f;
          const float p1 = (gl || key1 <= myq) ? __expf(s1[r] * 0.125f) : 0.f;
          lsum += p0 + p1;
          pf[r]     = (bf16)p0;
          pf[4 + r] = (bf16)p1;
        }

#pragma unroll
        for (int nt = 0; nt < 4; nt++) {
          const bf16x8 vf = *(const bf16x8*)(Vs + swz(g * 256 + nt * 64 + lane) * 8);
          o[nt] = __builtin_amdgcn_mfma_f32_16x16x32_bf16(pf, vf, o[nt], 0, 0, 0);
        }
      }
    }

    // reduce l across quads (lanes sharing l16), then store
    lsum += __shfl_xor(lsum, 16);
    lsum += __shfl_xor(lsum, 32);

#pragma unroll
    for (int r = 0; r < 4; r++) {
      const float inv = 1.0f / __shfl(lsum, quad * 4 + r);
      const int q = q0 + quad * 4 + r;
      const size_t rowoff = ((size_t)b * TSEQ + q) * HIDDEN + h * HDIM;
#pragma unroll
      for (int nt = 0; nt < 4; nt++)
        O[rowoff + nt * 16 + l16] = (bf16)(o[nt][r] * inv);
    }
  }
}

// ======================================================================
extern "C" void kernel_launch(void* const* d_in, const int* in_sizes, int n_in,
                              void* d_out, int out_size, void* d_ws, size_t ws_size,
                              hipStream_t stream)
{
  const float* x     = (const float*)d_in[0];
  const int*   ids   = (const int*)d_in[1];
  const float* qkv_w = (const float*)d_in[2];
  const float* qkv_b = (const float*)d_in[3];
  const float* out_w = (const float*)d_in[4];
  const float* out_b = (const float*)d_in[5];
  const int*   gidx  = (const int*)d_in[6];
  float* out = (float*)d_out;

  // ws (32 MiB): Q@0, K@8M, V@16M (O aliases V), slot24@24M multiplexed:
  //   xb (pre-gemm0) -> Vt (transpose..attn) -> out_wb (post-attn).
  // qkv_wb (6 MiB) lives in d_out (16.8 MiB, dead until gemm<1> rewrites it).
  char* ws = (char*)d_ws;
  bf16* Q      = (bf16*)(ws);
  bf16* Kb     = (bf16*)(ws + (size_t)(8u << 20));
  bf16* V      = (bf16*)(ws + (size_t)(16u << 20));
  bf16* slot24 = (bf16*)(ws + (size_t)(24u << 20));
  bf16* xb     = slot24;
  bf16* Vt     = slot24;
  bf16* out_wb = slot24;
  bf16* qkv_wb = (bf16*)d_out;
  bf16* O      = V;

  // 0) bulk-convert f32 inputs to bf16 (once)
  cvt_f32_bf16<<<2048, 256, 0, stream>>>(x, xb, MTOT * HIDDEN);
  cvt_f32_bf16<<<1536, 256, 0, stream>>>(qkv_w, qkv_wb, 3 * HIDDEN * HIDDEN);
  // 1) QKV projection -> Q/K/V (b,h,t,d)
  gemm_bt<0><<<dim3(3072 / 128, MTOT / 128), 256, 0, stream>>>(
      xb, qkv_wb, qkv_b, nullptr, Q, Kb, V, MTOT, 3 * HIDDEN, HIDDEN);
  // 2) RoPE in-place
  rope_kernel<<<(32 * TSEQ * 32) / 256, 256, 0, stream>>>(Q, Kb);
  // 3) V -> Vt (overwrites xb, dead)
  transpose_v<<<dim3(TSEQ / 64, 32), 256, 0, stream>>>(V, Vt);
  // 4) attention -> O (b,t,hidden); overwrites V
  attn_kernel<<<dim3(16, 32), 256, 0, stream>>>(Q, Kb, Vt, O, ids, gidx);
  // 5) convert out_w (overwrites Vt, dead)
  cvt_f32_bf16<<<512, 256, 0, stream>>>(out_w, out_wb, HIDDEN * HIDDEN);
  // 6) output projection -> d_out (overwrites qkv_wb, dead)
  gemm_bt<1><<<dim3(HIDDEN / 128, MTOT / 128), 256, 0, stream>>>(
      O, out_wb, out_b, out, nullptr, nullptr, nullptr, MTOT, HIDDEN, HIDDEN);
}